// Round 2
// baseline (160.163 us; speedup 1.0000x reference)
//
#include <hip/hip_runtime.h>
#include <cstdint>

typedef unsigned short ushortT;
typedef __attribute__((ext_vector_type(8))) short short8;      // 8 bf16 = 4 VGPRs (MFMA A/B frag)
typedef __attribute__((ext_vector_type(8))) unsigned short ushort8v;
typedef __attribute__((ext_vector_type(4))) float float4v;
typedef __attribute__((ext_vector_type(4))) unsigned int uint4v;

#define ATT_SCALE 0.17677669529663687f   // 32^-0.5

__device__ inline float bf2f(unsigned short u) {
    union { unsigned int i; float f; } x; x.i = ((unsigned int)u) << 16; return x.f;
}
__device__ inline unsigned short f2bf(float f) {
    union { float f; unsigned int i; } x; x.f = f;
    unsigned int i = x.i;
    i += 0x7fffu + ((i >> 16) & 1u);      // RNE
    return (unsigned short)(i >> 16);
}
// hardware packed fp32->bf16 RNE: low16 = bf16(a), high16 = bf16(b)
__device__ inline unsigned int cvtpk_bf16(float a, float b) {
    unsigned int r;
    asm("v_cvt_pk_bf16_f32 %0, %1, %2" : "=v"(r) : "v"(a), "v"(b));
    return r;
}

__device__ inline void gld_lds16(const ushortT* g, ushortT* l) {
    // async global->LDS, 16B/lane; LDS dest = wave-uniform base + lane*16
    __builtin_amdgcn_global_load_lds((const __attribute__((address_space(1))) void*)g,
                                     (__attribute__((address_space(3))) void*)l, 16, 0, 0);
}

// ---------------------------------------------------------------------------
// GEMM  D[m][n] = sum_k A[m][k] * Bt[n][k]  + bias   (fp32 acc), templated
// operand staging:
//   AMODE 1: A = fp32 row-major MxK weights; reg-stage + v_cvt_pk_bf16_f32.
//   AMODE 2: A = x (B,C,P) fp32 channel-major; fused TRANSPOSE+convert:
//            thread loads 8 float4 (4 contig pixels x 8 channels, 512B runs),
//            in-register transpose, 4x ds_write_b128 into the XOR-swizzled
//            tile (write aliasing 2-way = free; read path unchanged).
//   BMODE 1: Bt = bf16 head-major qkv (global_load_lds, 16B/lane).
//   BMODE 2: Bt = fp32 row-major NxK weights; reg-stage + convert.
// LDS layout per operand tile (128 rows x 64 elems): row r stride 64 elems,
// 8 chunk-slots of 8 bf16; content at slot s = global chunk (s ^ (r&7)) ->
// frag reads at slot (k8 ^ (r&7)) are bank-conflict-free.
// XCD-aware block swizzle; epilogues via 32 KB pool, coalesced 16B stores.
// ---------------------------------------------------------------------------
template<int AMODE, int BMODE>
__global__ __launch_bounds__(256) void gemm_bt(const void* __restrict__ Av,
                                               const void* __restrict__ Bv, long long sBb,
                                               int ldb,
                                               void* __restrict__ D, long long sDb,
                                               int ldd, int dHeadMajor, int outF32,
                                               const float* __restrict__ bias, int biasAlongM,
                                               int K, int swizzleMode) {
    __shared__ __align__(16) ushortT pool[16384];   // 32 KB: [A(16K)|B(16K)] / epilogue

    int mIdx, nIdx, bz;
    {
        int id = blockIdx.x;
        int r  = id & 7;
        int j  = id >> 3;
        if (swizzleMode == 0) {
            mIdx = r * 32 + j / 6;     // 6 n-blocks sharing an A-panel -> same XCD
            nIdx = j % 6;
            bz   = 0;
        } else {
            int p = r * 32 + (j >> 1); // 2 m-blocks sharing a y-tile -> same XCD
            bz   = p >> 5;
            nIdx = p & 31;
            mIdx = j & 1;
        }
    }
    const int n0 = nIdx * 128;
    const int m0 = mIdx * 128;

    const int t    = threadIdx.x;
    const int wv   = t >> 6;
    const int lane = t & 63;
    const int lm   = lane & 15;
    const int quad = lane >> 4;
    const int wm   = wv & 1;     // wave's 64-row quadrant (m)
    const int wn   = wv >> 1;    // wave's 64-col quadrant (n)

    ushortT* Als = pool;            // 128 rows x 64 elems
    ushortT* Bls = pool + 8192;

    // operand base pointers per mode
    const float*   Axf = nullptr;   // AMODE 2: x batch base (channel-major)
    int            pb  = 0;         // AMODE 2: pixel base within batch
    const float*   Awf = nullptr;   // AMODE 1: fp32 weights row-major
    const ushortT* Bh  = nullptr;   // BMODE 1: bf16 head-major
    const float*   Bwf = nullptr;   // BMODE 2: fp32 weights row-major
    if constexpr (AMODE == 2) {
        Axf = (const float*)Av + (size_t)(m0 >> 12) * (256 * 4096);
        pb  = m0 & 4095;
    } else {
        Awf = (const float*)Av;
    }
    if constexpr (BMODE == 1) {
        Bh = (const ushortT*)Bv + (size_t)bz * sBb;
    } else {
        Bwf = (const float*)Bv;
    }

    float4v acc[4][4];
#pragma unroll
    for (int i = 0; i < 4; i++)
#pragma unroll
        for (int j = 0; j < 4; j++) { float4v z = {0.f, 0.f, 0.f, 0.f}; acc[i][j] = z; }

    const int nkt = K >> 6;          // BK=64
    for (int kt = 0; kt < nkt; ++kt) {
        __syncthreads();   // previous stage's LDS reads complete before overwrite

        // ---- stage A ----
        if constexpr (AMODE == 2) {
            // fused transpose: 4 contig pixels x 8 contig channels per thread
            const int pg = t & 31;               // pixel group (4 px)
            const int cg = t >> 5;               // channel chunk 0..7
            const float* xs = Axf + (size_t)(kt * 64 + cg * 8) * 4096 + pb + pg * 4;
            float4v ld[8];
#pragma unroll
            for (int i = 0; i < 8; i++) ld[i] = *(const float4v*)(xs + (size_t)i * 4096);
#pragma unroll
            for (int j = 0; j < 4; j++) {        // one pixel (row) per round
                int r = pg * 4 + j;
                int s = cg ^ (r & 7);
                uint4v w;
                w.x = cvtpk_bf16(ld[0][j], ld[1][j]);
                w.y = cvtpk_bf16(ld[2][j], ld[3][j]);
                w.z = cvtpk_bf16(ld[4][j], ld[5][j]);
                w.w = cvtpk_bf16(ld[6][j], ld[7][j]);
                *(uint4v*)&Als[r * 64 + s * 8] = w;
            }
        } else if constexpr (AMODE == 1) {
            // fp32 row-major weights: 4 (row, chunk) units per thread
#pragma unroll
            for (int j = 0; j < 4; j++) {
                int u  = t + 256 * j;            // 0..1023
                int r  = u >> 3;
                int gc = u & 7;
                const float* gp = Awf + (size_t)(m0 + r) * K + kt * 64 + gc * 8;
                float4v a = *(const float4v*)gp;
                float4v b = *(const float4v*)(gp + 4);
                uint4v w;
                w.x = cvtpk_bf16(a[0], a[1]);
                w.y = cvtpk_bf16(a[2], a[3]);
                w.z = cvtpk_bf16(b[0], b[1]);
                w.w = cvtpk_bf16(b[2], b[3]);
                *(uint4v*)&Als[r * 64 + (gc ^ (r & 7)) * 8] = w;
            }
        }

        // ---- stage B ----
        if constexpr (BMODE == 1) {
#pragma unroll
            for (int j = 0; j < 4; j++) {
                int cid = wv * 256 + j * 64 + lane;   // chunk id in [0,1024)
                int row = cid >> 3;
                int s   = cid & 7;
                int gc  = s ^ (row & 7);
                const ushortT* gb =
                    Bh + ((size_t)(kt * 2 + (gc >> 2)) * 32768 + (n0 + row)) * 32 + (gc & 3) * 8;
                gld_lds16(gb, Bls + (size_t)(wv * 256 + j * 64) * 8);
            }
        } else if constexpr (BMODE == 2) {
#pragma unroll
            for (int j = 0; j < 4; j++) {
                int u  = t + 256 * j;
                int r  = u >> 3;
                int gc = u & 7;
                const float* gp = Bwf + (size_t)(n0 + r) * K + kt * 64 + gc * 8;
                float4v a = *(const float4v*)gp;
                float4v b = *(const float4v*)(gp + 4);
                uint4v w;
                w.x = cvtpk_bf16(a[0], a[1]);
                w.y = cvtpk_bf16(a[2], a[3]);
                w.z = cvtpk_bf16(b[0], b[1]);
                w.w = cvtpk_bf16(b[2], b[3]);
                *(uint4v*)&Bls[r * 64 + (gc ^ (r & 7)) * 8] = w;
            }
        }

        if constexpr (BMODE == 1) {
            asm volatile("s_waitcnt vmcnt(0)" ::: "memory");   // drain global_load_lds
        }
        __syncthreads();

#pragma unroll
        for (int g = 0; g < 2; g++) {            // k-group: k = g*32 .. g*32+31
            short8 af[4], bfr[4];
#pragma unroll
            for (int i = 0; i < 4; i++) {
                int r = wm * 64 + i * 16 + lm;
                int slot = (g * 4 + quad) ^ (r & 7);
                af[i] = *(const short8*)&Als[r * 64 + slot * 8];
            }
#pragma unroll
            for (int j = 0; j < 4; j++) {
                int r = wn * 64 + j * 16 + lm;
                int slot = (g * 4 + quad) ^ (r & 7);
                bfr[j] = *(const short8*)&Bls[r * 64 + slot * 8];
            }
#pragma unroll
            for (int i = 0; i < 4; i++)
#pragma unroll
                for (int j = 0; j < 4; j++)
                    acc[i][j] = __builtin_amdgcn_mfma_f32_16x16x32_bf16(af[i], bfr[j], acc[i][j], 0, 0, 0);
        }
    }

    // epilogue: C/D layout col = lane&15, row = quad*4 + reg
    if (dHeadMajor) {
        __syncthreads();   // all frag reads done before pool overwrite
#pragma unroll
        for (int i = 0; i < 4; i++) {
#pragma unroll
            for (int j = 0; j < 4; j++) {
                int c = wn * 64 + j * 16 + lm;
#pragma unroll
                for (int rg = 0; rg < 4; rg++) {
                    int r = wm * 64 + i * 16 + quad * 4 + rg;
                    float v = acc[i][j][rg] + bias[biasAlongM ? (m0 + r) : (n0 + c)];
                    int chunk = (c >> 3) ^ (r & 7);
                    pool[r * 128 + chunk * 8 + (c & 7)] = f2bf(v);
                }
            }
        }
        __syncthreads();
        ushortT* Dh = (ushortT*)D + (size_t)bz * sDb;
#pragma unroll
        for (int g = 0; g < 4; g++) {
            ushortT* base = Dh + ((size_t)((n0 >> 5) + g) * 32768 + m0) * 32;
#pragma unroll
            for (int it = 0; it < 2; it++) {
                int id = it * 256 + t;          // 0..511
                int r  = id >> 2;
                int cb = id & 3;                // 8-chunk within group
                int pch = (g * 4 + cb) ^ (r & 7);
                ushort8v v = *(const ushort8v*)&pool[r * 128 + pch * 8];
                *(ushort8v*)(base + r * 32 + cb * 8) = v;
            }
        }
    } else if (outF32) {
        // Two row-half passes: stage 64x128 fp32 (32 KB) with +4r column
        // rotation, then fully-coalesced float4 stores (512 B per row).
        float* poolF = (float*)pool;
        float* Df = (float*)D + (size_t)bz * sDb;
#pragma unroll
        for (int pass = 0; pass < 2; pass++) {
            __syncthreads();   // prior pool use (tiles / prev pass) complete
            if (wm == pass) {
#pragma unroll
                for (int i = 0; i < 4; i++) {
#pragma unroll
                    for (int j = 0; j < 4; j++) {
                        int c = wn * 64 + j * 16 + lm;
#pragma unroll
                        for (int rg = 0; rg < 4; rg++) {
                            int r64 = i * 16 + quad * 4 + rg;    // 0..63
                            float v = acc[i][j][rg] +
                                      bias[biasAlongM ? (m0 + pass * 64 + r64) : (n0 + c)];
                            int phys = (c + 4 * r64) & 127;      // rotation: 2-way banks
                            poolF[r64 * 128 + phys] = v;
                        }
                    }
                }
            }
            __syncthreads();
#pragma unroll
            for (int it = 0; it < 8; it++) {
                int id  = it * 256 + t;          // 0..2047
                int r64 = id >> 5;               // 0..63
                int c   = (id & 31) * 4;         // logical float4 col
                int phys = (c + 4 * r64) & 127;  // stays 16B-aligned
                float4v v = *(const float4v*)&poolF[r64 * 128 + phys];
                *(float4v*)&Df[(size_t)(m0 + pass * 64 + r64) * ldd + n0 + c] = v;
            }
        }
    } else {
        ushortT* Dh = (ushortT*)D + (size_t)bz * sDb;
#pragma unroll
        for (int i = 0; i < 4; i++) {
            int r0 = m0 + wm * 64 + i * 16 + quad * 4;
#pragma unroll
            for (int j = 0; j < 4; j++) {
                int c = n0 + wn * 64 + j * 16 + lm;
#pragma unroll
                for (int rg = 0; rg < 4; rg++) {
                    int r = r0 + rg;
                    float v = acc[i][j][rg] + bias[biasAlongM ? r : c];
                    Dh[(size_t)r * ldd + c] = f2bf(v);
                }
            }
        }
    }
}

// ---------------------------------------------------------------------------
// Multi-dilated 3x3 local attention, IN-PLACE on HEAD-MAJOR bf16 qkv:
// qkv[(part*8+hd)*32768 + bp][32], part in {q,k,v}.
// FOUR lanes per pixel (channel quarter each): 16384 waves, ~55 persistent
// VGPRs -> 8 waves/SIMD residency. A 4-lane group covers one pixel's
// contiguous 64B of k/v -> a wave reads a contiguous 1 KB segment per
// neighbor. Logit dot reduced across the quad with 2x __shfl_xor; softmax
// recomputed redundantly in all 4 lanes. OOB: logit exactly 0 stays in the
// denominator, v = 0. Thread writes only its own q quarter -> race-free.
// ---------------------------------------------------------------------------
__global__ __launch_bounds__(256, 8) void attn_k(ushortT* qkv) {
    const int gt      = blockIdx.x * 256 + threadIdx.x;
    const int quarter = gt & 3;          // channel quarter 0..3
    const int pix     = gt >> 2;         // 0..262143
    const int hd      = pix >> 15;       // 0..7  (32768 pixels per head)
    const int rem     = pix & 32767;
    const int b       = rem >> 12;
    const int p       = rem & 4095;      // wave covers 16 consecutive p -> h uniform
    const int h       = p >> 6;
    const int w       = p & 63;
    const int dil     = (hd & 3) + 1;    // DILATIONS = [1,2,3,4]
    const int c0      = quarter * 8;

    ushortT*       qp    = qkv + ((size_t)hd * 32768 + (size_t)b * 4096 + p) * 32 + c0;
    const ushortT* kbase = qkv + ((size_t)(8  + hd) * 32768 + (size_t)b * 4096) * 32 + c0;
    const ushortT* vbase = qkv + ((size_t)(16 + hd) * 32768 + (size_t)b * 4096) * 32 + c0;

    float q[8];
    {
        ushort8v v = *(const ushort8v*)qp;
#pragma unroll
        for (int j = 0; j < 8; j++) q[j] = bf2f(v[j]);
    }

    float lgt[9];
    int   nb[9];
    unsigned vmask = 0;
#pragma unroll
    for (int ii = 0; ii < 3; ii++) {
#pragma unroll
        for (int jj = 0; jj < 3; jj++) {
            int idx = ii * 3 + jj;
            int hh = h + (ii - 1) * dil;   // wave-uniform
            int ww = w + (jj - 1) * dil;   // group-uniform (same pixel in all 4 lanes)
            bool ok = ((unsigned)hh < 64u) && ((unsigned)ww < 64u);
            int pp = (hh << 6) + ww;
            nb[idx] = pp;
            float l = 0.f;                 // OOB: k is zero-padded -> logit exactly 0
            if (ok) {
                vmask |= (1u << idx);
                ushort8v v = *(const ushort8v*)(kbase + (size_t)pp * 32);
#pragma unroll
                for (int j = 0; j < 8; j++) l += q[j] * bf2f(v[j]);
            }
            lgt[idx] = l;
        }
    }
    // quad reduce: lanes 4i..4i+3 hold partial dots of the same pixel.
    // OOB groups reduce 0+0+0+0 = 0 -> semantics preserved.
#pragma unroll
    for (int i = 0; i < 9; i++) {
        float l = lgt[i];
        l += __shfl_xor(l, 1);
        l += __shfl_xor(l, 2);
        lgt[i] = l * ATT_SCALE;
    }

    float mx = lgt[0];
#pragma unroll
    for (int i = 1; i < 9; i++) mx = fmaxf(mx, lgt[i]);
    float e[9], s = 0.f;
#pragma unroll
    for (int i = 0; i < 9; i++) { e[i] = __expf(lgt[i] - mx); s += e[i]; }
    const float inv = 1.f / s;

    float acc[8];
#pragma unroll
    for (int d = 0; d < 8; d++) acc[d] = 0.f;
#pragma unroll
    for (int idx = 0; idx < 9; idx++) {
        if ((vmask >> idx) & 1u) {        // OOB: v = 0, contributes nothing (e[idx] stays in s)
            float pj = e[idx] * inv;
            ushort8v v = *(const ushort8v*)(vbase + (size_t)nb[idx] * 32);
#pragma unroll
            for (int j = 0; j < 8; j++) acc[j] += pj * bf2f(v[j]);
        }
    }

    {
        ushort8v v;
#pragma unroll
        for (int j = 0; j < 8; j++) v[j] = f2bf(acc[j]);
        *(ushort8v*)qp = v;               // overwrite own q quarter
    }
}

// ---------------------------------------------------------------------------
extern "C" void kernel_launch(void* const* d_in, const int* in_sizes, int n_in,
                              void* d_out, int out_size, void* d_ws, size_t ws_size,
                              hipStream_t stream) {
    const float* x      = (const float*)d_in[0];  // (8,256,64,64) fp32
    const float* w_qkv  = (const float*)d_in[1];  // (768,256) fp32
    const float* b_qkv  = (const float*)d_in[2];  // (768,) fp32
    const float* w_proj = (const float*)d_in[3];  // (256,256) fp32
    const float* b_proj = (const float*)d_in[4];  // (256,) fp32

    // ws layout: qkv head-major bf16 only: 24 x 32768 x 32 = 48 MiB
    ushortT* qkv = (ushortT*)d_ws;

    // 1) qkv head-major = x^T(32768,256) @ w_qkv^T + b_qkv   (bias along n)
    //    fused transpose+convert of x and convert of w_qkv in the staging
    //    phase. 1536 blocks, XCD swizzle mode 0 (6 n-blocks per A-panel).
    gemm_bt<2, 2><<<dim3(1536), 256, 0, stream>>>(x, w_qkv, 0, 256,
                                                  qkv, 0, 0, 1, 0,
                                                  b_qkv, 0, 256, 0);

    // 2) attention in-place on head-major qkv (y overwrites q quarters)
    //    4 lanes per pixel: 1,048,576 threads = 16384 waves (8/SIMD resident)
    attn_k<<<dim3(4096), 256, 0, stream>>>(qkv);

    // 3) out(b,256,4096) fp32 = w_proj @ y(b)^T + b_proj  (bias along m)
    //    w_proj converted on stage. 512 blocks, XCD swizzle mode 1.
    gemm_bt<1, 1><<<dim3(512), 256, 0, stream>>>(w_proj, qkv, (long long)4096 * 32, 0,
                                                 d_out, (long long)256 * 4096, 4096, 0, 1,
                                                 b_proj, 1, 256, 1);
}